// Round 7
// baseline (7644.715 us; speedup 1.0000x reference)
//
#include <hip/hip_runtime.h>
#include <hip/hip_bf16.h>

#define B 32
#define S 512
#define H 1024
#define G 4096          // 4*H
#define NBLK 256
#define HSLOT 65536     // shorts per h slot (2 dirs x B x H)

typedef __attribute__((ext_vector_type(8))) short bf16x8;
typedef __attribute__((ext_vector_type(8))) unsigned short u16x8;
typedef __attribute__((ext_vector_type(4))) float f32x4;

__device__ __forceinline__ unsigned short f2bf(float v) {
    __hip_bfloat16 b = __float2bfloat16(v);
    return *reinterpret_cast<unsigned short*>(&b);
}
__device__ __forceinline__ float bf2f(unsigned short u) {
    union { float f; unsigned int i; } v; v.i = ((unsigned int)u) << 16; return v.f;
}
#define MFMA(a, b, c) __builtin_amdgcn_mfma_f32_16x16x32_bf16(a, b, c, 0, 0, 0)

// =====================================================================
// prep_weights: fragment-ordered bf16 weights for one matrix pair (fw,bw).
// chunk idx = ((blk*4 + w)*16 + f)*64 + lane, 8 bf16/chunk; 1,048,576 chunks.
// =====================================================================
__global__ __launch_bounds__(256)
void prep_weights(const float* __restrict__ fw, const float* __restrict__ bw,
                  unsigned short* __restrict__ dst)
{
    size_t idx = (size_t)blockIdx.x * 256 + threadIdx.x;
    int lane = idx & 63;
    int f    = (idx >> 6) & 15;
    int w    = (idx >> 10) & 3;
    int blk  = (int)(idx >> 12);
    int dir  = blk >> 7, jg = blk & 127;
    int ks = f >> 1, ct = f & 1;

    int c  = ct * 16 + (lane & 15);
    int g  = (c >> 3) * H + jg * 8 + (c & 7);
    int kk = w * 256 + ks * 32 + ((lane >> 4) * 8);

    const float* src = dir ? bw : fw;
    u16x8 o;
#pragma unroll
    for (int i = 0; i < 8; ++i)
        o[i] = f2bf(src[(size_t)(kk + i) * G + g]);
    *(u16x8*)&dst[idx * 8] = o;
}

__global__ __launch_bounds__(256)
void prep_x(const float* __restrict__ x, unsigned short* __restrict__ xbf)
{
    size_t i8 = ((size_t)blockIdx.x * 256 + threadIdx.x) * 8;
    float4 v0 = *(const float4*)&x[i8];
    float4 v1 = *(const float4*)&x[i8 + 4];
    u16x8 o;
    o[0] = f2bf(v0.x); o[1] = f2bf(v0.y); o[2] = f2bf(v0.z); o[3] = f2bf(v0.w);
    o[4] = f2bf(v1.x); o[5] = f2bf(v1.y); o[6] = f2bf(v1.z); o[7] = f2bf(v1.w);
    *(u16x8*)&xbf[i8] = o;
}

// =====================================================================
// lstm_persist: one cooperative kernel, all 512 steps, no __syncthreads
// in the loop.
// 256 blocks x 512 threads. Block (dir,jg) owns 32 gate-cols.
// Waves 0-3 (U+gate): per step t:
//   wave0 polls gen[dir] >= 128*t (single LLC line) -> LDS token;
//   h(t-1) @ U (regular pipelined loads from hhist[t], U frags in LDS);
//   LDS counter barrier among the 4 waves; gate: ring + partials -> h,c;
//   h -> hhist[t+1] via 8B agent stores; vmcnt(0); gcnt++; 4th wave
//   fetch_adds gen[dir]; dout stores issued after publication.
// Waves 4-7 (W): free-running fs-loop (fs = wave-4, +4 each iter): full-K
//   x@W+b -> ring[fs&7] (LDS), paced by gcnt (slot freed when gate passed
//   fs-8), published via ring_ready generation flags. Never on the
//   critical path (>=4-step slack).
// =====================================================================
__global__ __launch_bounds__(512, 1)
void lstm_persist(const unsigned short* __restrict__ wbufU,
                  const unsigned short* __restrict__ wbufW,
                  const unsigned short* __restrict__ xbf,
                  unsigned short* __restrict__ hhist,  // 513 slots x HSLOT
                  unsigned int* __restrict__ gen,      // [dir*32]
                  const float* __restrict__ pad,
                  const float* __restrict__ bfw, const float* __restrict__ bbw,
                  float* __restrict__ dout)
{
    const int blk = blockIdx.x;
    const int dir = blk >> 7;
    const int jg  = blk & 127;
    const int j0  = jg * 8;
    const int tid = threadIdx.x;
    const int wave = tid >> 6;
    const int lane = tid & 63;

    __shared__ short Uw[32768];                  // 64 KB U frags (wave-local regions)
    __shared__ float red[4][2][16][33];          // U partials
    __shared__ unsigned short ring[8][32][36];   // xz lookahead (bf16, bias folded)
    __shared__ unsigned rcnt;                    // red arrivals (monotone, 4/step)
    __shared__ unsigned gcnt;                    // gate-wave publishes (monotone, 4/step)
    __shared__ unsigned tok;                     // gen-poll relay
    __shared__ int ring_ready[8];                // slot generation = fs+1

    if (tid == 0) { rcnt = 0; gcnt = 0; tok = 0; }
    if (tid < 8) ring_ready[tid] = 0;
    __syncthreads();   // the only block-wide barrier (init)

    const int arow  = lane & 15;
    const int akoff = (lane >> 4) * 8;
    const int drow  = (lane >> 4) * 4;
    const int dcol  = lane & 15;
    const float* bsrc = dir ? bbw : bfw;
    const float wb0 = bsrc[(dcol >> 3) * H + j0 + (dcol & 7)];
    const float wb1 = bsrc[(((16 + dcol) >> 3)) * H + j0 + ((16 + dcol) & 7)];

    if (wave < 4) {
        // ---- load this wave's U region into LDS (16 KB, wave-local) ----
        {
            const unsigned short* src = wbufU + (((size_t)blk * 4 + wave) * 16) * 512 + lane * 8;
#pragma unroll
            for (int f = 0; f < 16; ++f)
                *(u16x8*)&Uw[((wave * 16 + f) * 64 + lane) * 8] = *(const u16x8*)(src + f * 512);
        }

        float hst = 0.f, cst = 0.f;
        const int gb  = (tid >> 3) & 31;
        const int gj  = tid & 7;
        const int gbt = gb >> 4, grow = gb & 15;
        const f32x4 zero4 = {0.f, 0.f, 0.f, 0.f};

        for (int t = 0; t < S; ++t) {
            const int s = dir ? (S - 1 - t) : t;
            float pv = pad[gb * S + s];      // early issue, hidden under poll/MFMA

            // ---- wait for step t-1 publications of this direction ----
            if (t) {
                if (wave == 0) {
                    const unsigned tgt = (unsigned)(128 * t);
                    while (__hip_atomic_load(&gen[dir * 32], __ATOMIC_RELAXED,
                                             __HIP_MEMORY_SCOPE_AGENT) < tgt)
                        __builtin_amdgcn_s_sleep(1);
                    asm volatile("" ::: "memory");
                    if (lane == 0) *(volatile unsigned*)&tok = (unsigned)t;
                } else {
                    while (*(volatile unsigned*)&tok < (unsigned)t) {}
                }
                asm volatile("" ::: "memory");
            }

            // ---- U phase: h(t-1) @ U, K-slice wave*256, regular loads ----
            f32x4 u00 = zero4, u01 = zero4, u10 = zero4, u11 = zero4;
            const unsigned short* hb = hhist + (size_t)t * HSLOT
                                     + ((size_t)(dir * B) + arow) * H + wave * 256 + akoff;
#pragma unroll
            for (int ks = 0; ks < 8; ++ks) {
                bf16x8 a0 = *(const bf16x8*)(hb + ks * 32);
                bf16x8 a1 = *(const bf16x8*)(hb + 16 * H + ks * 32);
                bf16x8 b0 = *(const bf16x8*)&Uw[((wave * 16 + ks * 2 + 0) * 64 + lane) * 8];
                bf16x8 b1 = *(const bf16x8*)&Uw[((wave * 16 + ks * 2 + 1) * 64 + lane) * 8];
                u00 = MFMA(a0, b0, u00); u01 = MFMA(a0, b1, u01);
                u10 = MFMA(a1, b0, u10); u11 = MFMA(a1, b1, u11);
            }
#pragma unroll
            for (int r = 0; r < 4; ++r) {
                red[wave][0][drow + r][dcol]      = u00[r];
                red[wave][0][drow + r][16 + dcol] = u01[r];
                red[wave][1][drow + r][dcol]      = u10[r];
                red[wave][1][drow + r][16 + dcol] = u11[r];
            }
            asm volatile("s_waitcnt lgkmcnt(0)" ::: "memory");
            if (lane == 0) atomicAdd(&rcnt, 1u);
            {
                const unsigned need = 4u * (unsigned)(t + 1);
                while (*(volatile unsigned*)&rcnt < need) {}
                asm volatile("" ::: "memory");
            }

            // ---- wait for ring slot t (normally ready long ago) ----
            while (*(volatile int*)&ring_ready[t & 7] < t + 1) {}
            asm volatile("" ::: "memory");

            // ---- gate ----
            float z[4];
#pragma unroll
            for (int q = 0; q < 4; ++q) {
                const int c = q * 8 + gj;
                float zz = bf2f(ring[t & 7][gb][c]);
#pragma unroll
                for (int w = 0; w < 4; ++w) zz += red[w][gbt][grow][c];
                z[q] = zz;
            }
            float ig = 1.f / (1.f + expf(-z[0]));
            float fg = 1.f / (1.f + expf(-z[1]));
            float gg = tanhf(z[2]);
            float og = 1.f / (1.f + expf(-z[3]));

            float m  = 1.f - pv;
            float cn = fg * cst + ig * gg;
            float hn = og * tanhf(cn);
            float h2 = fmaf(m, hn - hst, hst);
            float c2 = fmaf(m, cn - cst, cst);
            hst = h2; cst = c2;

            // ---- publish h(t) -> hhist[t+1] (8B packed agent stores) ----
            unsigned u = (unsigned)f2bf(h2);
            const int gl = lane & ~3;
            unsigned v0 = (unsigned)__shfl((int)u, gl + 0);
            unsigned v1 = (unsigned)__shfl((int)u, gl + 1);
            unsigned v2 = (unsigned)__shfl((int)u, gl + 2);
            unsigned v3 = (unsigned)__shfl((int)u, gl + 3);
            if ((lane & 3) == 0) {
                unsigned long long pk = (unsigned long long)(v0 & 0xffffu)
                                      | ((unsigned long long)(v1 & 0xffffu) << 16)
                                      | ((unsigned long long)(v2 & 0xffffu) << 32)
                                      | ((unsigned long long)(v3 & 0xffffu) << 48);
                unsigned long long* hp = (unsigned long long*)
                    (hhist + (size_t)(t + 1) * HSLOT
                           + ((size_t)(dir * B) + gb) * H + j0 + gj);
                __hip_atomic_store(hp, pk, __ATOMIC_RELAXED, __HIP_MEMORY_SCOPE_AGENT);
            }
            asm volatile("s_waitcnt vmcnt(0)" ::: "memory");
            if (lane == 0) {
                unsigned old = atomicAdd(&gcnt, 1u);
                if (old == 4u * (unsigned)t + 3u)
                    __hip_atomic_fetch_add(&gen[dir * 32], 1u,
                                           __ATOMIC_RELAXED, __HIP_MEMORY_SCOPE_AGENT);
            }

            // ---- dout (off the publication path) ----
            dout[((size_t)gb * S + s) * (2 * H) + dir * H + j0 + gj] = h2;
            if (t == S - 1) {
                size_t base = (size_t)B * S * 2 * H;
                dout[base + dir * 2 * B * H + gb * H + j0 + gj] = h2;
                dout[base + dir * 2 * B * H + B * H + gb * H + j0 + gj] = c2;
            }
        }
    } else {
        // ---- W waves: free-running xz producer, fs = wave-4, +4 ----
        const f32x4 zero4 = {0.f, 0.f, 0.f, 0.f};
        for (int fs = wave - 4; fs < S; fs += 4) {
            if (fs >= 8) {   // wait until gate passed step fs-8 (slot free)
                const unsigned need = 4u * (unsigned)(fs - 7);
                while (*(volatile unsigned*)&gcnt < need)
                    __builtin_amdgcn_s_sleep(1);
                asm volatile("" ::: "memory");
            }
            const int s2 = dir ? (S - 1 - fs) : fs;
            f32x4 a00 = zero4, a01 = zero4, a10 = zero4, a11 = zero4;
            for (int sl = 0; sl < 4; ++sl) {
                const unsigned short* wbase =
                    wbufW + (((size_t)blk * 4 + sl) * 16) * 512 + lane * 8;
                bf16x8 wf[16];
#pragma unroll
                for (int f = 0; f < 16; ++f) wf[f] = *(const bf16x8*)(wbase + f * 512);
                const unsigned short* A0 =
                    xbf + ((size_t)arow * S + s2) * H + sl * 256 + akoff;
#pragma unroll
                for (int ks = 0; ks < 8; ++ks) {
                    bf16x8 x0 = *(const bf16x8*)(A0 + ks * 32);
                    bf16x8 x1 = *(const bf16x8*)(A0 + (size_t)16 * S * H + ks * 32);
                    a00 = MFMA(x0, wf[ks*2+0], a00); a01 = MFMA(x0, wf[ks*2+1], a01);
                    a10 = MFMA(x1, wf[ks*2+0], a10); a11 = MFMA(x1, wf[ks*2+1], a11);
                }
            }
            const int slot = fs & 7;
#pragma unroll
            for (int r = 0; r < 4; ++r) {
                ring[slot][drow + r][dcol]           = f2bf(a00[r] + wb0);
                ring[slot][drow + r][16 + dcol]      = f2bf(a01[r] + wb1);
                ring[slot][16 + drow + r][dcol]      = f2bf(a10[r] + wb0);
                ring[slot][16 + drow + r][16 + dcol] = f2bf(a11[r] + wb1);
            }
            asm volatile("s_waitcnt lgkmcnt(0)" ::: "memory");
            if (lane == 0) *(volatile int*)&ring_ready[slot] = fs + 1;
        }
    }
}

// =====================================================================
// Host side
// =====================================================================
extern "C" void kernel_launch(void* const* d_in, const int* in_sizes, int n_in,
                              void* d_out, int out_size, void* d_ws, size_t ws_size,
                              hipStream_t stream)
{
    const float* x   = (const float*)d_in[0];
    const float* pad = (const float*)d_in[1];
    const float* Wfw = (const float*)d_in[2];
    const float* Ufw = (const float*)d_in[3];
    const float* bfw = (const float*)d_in[4];
    const float* Wbw = (const float*)d_in[5];
    const float* Ubw = (const float*)d_in[6];
    const float* bbw = (const float*)d_in[7];
    float* out = (float*)d_out;

    char* w = (char*)d_ws;
    unsigned short* wbufW = (unsigned short*)w;                     // 16.8 MB
    unsigned short* wbufU = wbufW + (size_t)1048576 * 8;            // 16.8 MB
    unsigned short* xbf   = wbufU + (size_t)1048576 * 8;            // 33.6 MB
    unsigned short* hhist = xbf + (size_t)B * S * H;                // 513 x 128 KB
    unsigned int*   gen   = (unsigned int*)(hhist + (size_t)(S + 1) * HSLOT); // 64 uints

    // zero h slot 0 and gen counters (deterministic per call)
    hipMemsetAsync(hhist, 0, (size_t)HSLOT * sizeof(unsigned short), stream);
    hipMemsetAsync(gen, 0, 64 * sizeof(unsigned int), stream);

    prep_x<<<8192, 256, 0, stream>>>(x, xbf);
    prep_weights<<<4096, 256, 0, stream>>>(Wfw, Wbw, wbufW);
    prep_weights<<<4096, 256, 0, stream>>>(Ufw, Ubw, wbufU);

    void* args[] = { (void*)&wbufU, (void*)&wbufW, (void*)&xbf, (void*)&hhist,
                     (void*)&gen, (void*)&pad,
                     (void*)&bfw, (void*)&bbw, (void*)&out };
    hipLaunchCooperativeKernel((void*)lstm_persist, dim3(NBLK), dim3(512),
                               args, 0, stream);
}

// Round 8
// 7368.478 us; speedup vs baseline: 1.0375x; 1.0375x over previous
//
#include <hip/hip_runtime.h>
#include <hip/hip_bf16.h>

#define B 32
#define S 512
#define H 1024
#define G 4096          // 4*H
#define NBLK 256
#define HSLOT 65536     // shorts per h slot (2 dirs x B x H)

typedef __attribute__((ext_vector_type(8))) short bf16x8;
typedef __attribute__((ext_vector_type(8))) unsigned short u16x8;
typedef __attribute__((ext_vector_type(4))) float f32x4;

__device__ __forceinline__ unsigned short f2bf(float v) {
    __hip_bfloat16 b = __float2bfloat16(v);
    return *reinterpret_cast<unsigned short*>(&b);
}
__device__ __forceinline__ float bf2f(unsigned short u) {
    union { float f; unsigned int i; } v; v.i = ((unsigned int)u) << 16; return v.f;
}
#define MFMA(a, b, c) __builtin_amdgcn_mfma_f32_16x16x32_bf16(a, b, c, 0, 0, 0)

// =====================================================================
// prep_weights: fragment-ordered bf16 weights for one matrix pair (fw,bw).
// chunk idx = ((blk*4 + w)*16 + f)*64 + lane, 8 bf16/chunk; 1,048,576 chunks.
// =====================================================================
__global__ __launch_bounds__(256)
void prep_weights(const float* __restrict__ fw, const float* __restrict__ bw,
                  unsigned short* __restrict__ dst)
{
    size_t idx = (size_t)blockIdx.x * 256 + threadIdx.x;
    int lane = idx & 63;
    int f    = (idx >> 6) & 15;
    int w    = (idx >> 10) & 3;
    int blk  = (int)(idx >> 12);
    int dir  = blk >> 7, jg = blk & 127;
    int ks = f >> 1, ct = f & 1;

    int c  = ct * 16 + (lane & 15);
    int g  = (c >> 3) * H + jg * 8 + (c & 7);
    int kk = w * 256 + ks * 32 + ((lane >> 4) * 8);

    const float* src = dir ? bw : fw;
    u16x8 o;
#pragma unroll
    for (int i = 0; i < 8; ++i)
        o[i] = f2bf(src[(size_t)(kk + i) * G + g]);
    *(u16x8*)&dst[idx * 8] = o;
}

__global__ __launch_bounds__(256)
void prep_x(const float* __restrict__ x, unsigned short* __restrict__ xbf)
{
    size_t i8 = ((size_t)blockIdx.x * 256 + threadIdx.x) * 8;
    float4 v0 = *(const float4*)&x[i8];
    float4 v1 = *(const float4*)&x[i8 + 4];
    u16x8 o;
    o[0] = f2bf(v0.x); o[1] = f2bf(v0.y); o[2] = f2bf(v0.z); o[3] = f2bf(v0.w);
    o[4] = f2bf(v1.x); o[5] = f2bf(v1.y); o[6] = f2bf(v1.z); o[7] = f2bf(v1.w);
    *(u16x8*)&xbf[i8] = o;
}

// =====================================================================
// lstm_persist: one cooperative kernel, all 512 steps, no __syncthreads
// in the loop.
// 256 blocks x 512 threads. Block (dir,jg) owns 32 gate-cols.
// Waves 0-3 (U+gate): per step t:
//   wave0 polls gen[dir] >= 128*t (single LLC line) -> LDS token;
//   h(t-1) @ U (regular pipelined loads from hhist[t], U frags in LDS);
//   LDS counter barrier among the 4 waves; gate: ring + partials -> h,c;
//   h -> hhist[t+1] via 8B agent stores; vmcnt(0); gcnt++; 4th wave
//   fetch_adds gen[dir]; dout stores issued after publication.
// Waves 4-7 (W): free-running fs-loop (fs = wave-4, +4 each iter): full-K
//   x@W+b -> ring[fs&7] (LDS), paced by gcnt (slot freed when gate passed
//   fs-8), published via ring_ready generation flags. Never on the
//   critical path (>=4-step slack).
// =====================================================================
__global__ __launch_bounds__(512, 1)
void lstm_persist(const unsigned short* __restrict__ wbufU,
                  const unsigned short* __restrict__ wbufW,
                  const unsigned short* __restrict__ xbf,
                  unsigned short* __restrict__ hhist,  // 513 slots x HSLOT
                  unsigned int* __restrict__ gen,      // [dir*32]
                  const float* __restrict__ pad,
                  const float* __restrict__ bfw, const float* __restrict__ bbw,
                  float* __restrict__ dout)
{
    const int blk = blockIdx.x;
    const int dir = blk >> 7;
    const int jg  = blk & 127;
    const int j0  = jg * 8;
    const int tid = threadIdx.x;
    const int wave = tid >> 6;
    const int lane = tid & 63;

    __shared__ short Uw[32768];                  // 64 KB U frags (wave-local regions)
    __shared__ float red[4][2][16][33];          // U partials
    __shared__ unsigned short ring[8][32][36];   // xz lookahead (bf16, bias folded)
    __shared__ unsigned rcnt;                    // red arrivals (monotone, 4/step)
    __shared__ unsigned gcnt;                    // gate-wave publishes (monotone, 4/step)
    __shared__ unsigned tok;                     // gen-poll relay
    __shared__ int ring_ready[8];                // slot generation = fs+1

    if (tid == 0) { rcnt = 0; gcnt = 0; tok = 0; }
    if (tid < 8) ring_ready[tid] = 0;
    __syncthreads();   // the only block-wide barrier (init)

    const int arow  = lane & 15;
    const int akoff = (lane >> 4) * 8;
    const int drow  = (lane >> 4) * 4;
    const int dcol  = lane & 15;
    const float* bsrc = dir ? bbw : bfw;
    const float wb0 = bsrc[(dcol >> 3) * H + j0 + (dcol & 7)];
    const float wb1 = bsrc[(((16 + dcol) >> 3)) * H + j0 + ((16 + dcol) & 7)];

    if (wave < 4) {
        // ---- load this wave's U region into LDS (16 KB, wave-local) ----
        {
            const unsigned short* src = wbufU + (((size_t)blk * 4 + wave) * 16) * 512 + lane * 8;
#pragma unroll
            for (int f = 0; f < 16; ++f)
                *(u16x8*)&Uw[((wave * 16 + f) * 64 + lane) * 8] = *(const u16x8*)(src + f * 512);
        }

        float hst = 0.f, cst = 0.f;
        const int gb  = (tid >> 3) & 31;
        const int gj  = tid & 7;
        const int gbt = gb >> 4, grow = gb & 15;
        const f32x4 zero4 = {0.f, 0.f, 0.f, 0.f};

        for (int t = 0; t < S; ++t) {
            const int s = dir ? (S - 1 - t) : t;
            float pv = pad[gb * S + s];      // early issue, hidden under poll/MFMA

            // ---- wait for step t-1 publications of this direction ----
            if (t) {
                if (wave == 0) {
                    const unsigned tgt = (unsigned)(128 * t);
                    while (__hip_atomic_load(&gen[dir * 32], __ATOMIC_RELAXED,
                                             __HIP_MEMORY_SCOPE_AGENT) < tgt)
                        __builtin_amdgcn_s_sleep(1);
                    asm volatile("" ::: "memory");
                    if (lane == 0) *(volatile unsigned*)&tok = (unsigned)t;
                } else {
                    while (*(volatile unsigned*)&tok < (unsigned)t) {}
                }
                asm volatile("" ::: "memory");
            }

            // ---- U phase: h(t-1) @ U, K-slice wave*256, regular loads ----
            f32x4 u00 = zero4, u01 = zero4, u10 = zero4, u11 = zero4;
            const unsigned short* hb = hhist + (size_t)t * HSLOT
                                     + ((size_t)(dir * B) + arow) * H + wave * 256 + akoff;
#pragma unroll
            for (int ks = 0; ks < 8; ++ks) {
                bf16x8 a0 = *(const bf16x8*)(hb + ks * 32);
                bf16x8 a1 = *(const bf16x8*)(hb + 16 * H + ks * 32);
                bf16x8 b0 = *(const bf16x8*)&Uw[((wave * 16 + ks * 2 + 0) * 64 + lane) * 8];
                bf16x8 b1 = *(const bf16x8*)&Uw[((wave * 16 + ks * 2 + 1) * 64 + lane) * 8];
                u00 = MFMA(a0, b0, u00); u01 = MFMA(a0, b1, u01);
                u10 = MFMA(a1, b0, u10); u11 = MFMA(a1, b1, u11);
            }
#pragma unroll
            for (int r = 0; r < 4; ++r) {
                red[wave][0][drow + r][dcol]      = u00[r];
                red[wave][0][drow + r][16 + dcol] = u01[r];
                red[wave][1][drow + r][dcol]      = u10[r];
                red[wave][1][drow + r][16 + dcol] = u11[r];
            }
            asm volatile("s_waitcnt lgkmcnt(0)" ::: "memory");
            if (lane == 0) atomicAdd(&rcnt, 1u);
            {
                const unsigned need = 4u * (unsigned)(t + 1);
                while (*(volatile unsigned*)&rcnt < need) {}
                asm volatile("" ::: "memory");
            }

            // ---- wait for ring slot t (normally ready long ago) ----
            while (*(volatile int*)&ring_ready[t & 7] < t + 1) {}
            asm volatile("" ::: "memory");

            // ---- gate ----
            float z[4];
#pragma unroll
            for (int q = 0; q < 4; ++q) {
                const int c = q * 8 + gj;
                float zz = bf2f(ring[t & 7][gb][c]);
#pragma unroll
                for (int w = 0; w < 4; ++w) zz += red[w][gbt][grow][c];
                z[q] = zz;
            }
            float ig = 1.f / (1.f + expf(-z[0]));
            float fg = 1.f / (1.f + expf(-z[1]));
            float gg = tanhf(z[2]);
            float og = 1.f / (1.f + expf(-z[3]));

            float m  = 1.f - pv;
            float cn = fg * cst + ig * gg;
            float hn = og * tanhf(cn);
            float h2 = fmaf(m, hn - hst, hst);
            float c2 = fmaf(m, cn - cst, cst);
            hst = h2; cst = c2;

            // ---- publish h(t) -> hhist[t+1] (8B packed agent stores) ----
            unsigned u = (unsigned)f2bf(h2);
            const int gl = lane & ~3;
            unsigned v0 = (unsigned)__shfl((int)u, gl + 0);
            unsigned v1 = (unsigned)__shfl((int)u, gl + 1);
            unsigned v2 = (unsigned)__shfl((int)u, gl + 2);
            unsigned v3 = (unsigned)__shfl((int)u, gl + 3);
            if ((lane & 3) == 0) {
                unsigned long long pk = (unsigned long long)(v0 & 0xffffu)
                                      | ((unsigned long long)(v1 & 0xffffu) << 16)
                                      | ((unsigned long long)(v2 & 0xffffu) << 32)
                                      | ((unsigned long long)(v3 & 0xffffu) << 48);
                unsigned long long* hp = (unsigned long long*)
                    (hhist + (size_t)(t + 1) * HSLOT
                           + ((size_t)(dir * B) + gb) * H + j0 + gj);
                __hip_atomic_store(hp, pk, __ATOMIC_RELAXED, __HIP_MEMORY_SCOPE_AGENT);
            }
            asm volatile("s_waitcnt vmcnt(0)" ::: "memory");
            if (lane == 0) {
                unsigned old = atomicAdd(&gcnt, 1u);
                if (old == 4u * (unsigned)t + 3u)
                    __hip_atomic_fetch_add(&gen[dir * 32], 1u,
                                           __ATOMIC_RELAXED, __HIP_MEMORY_SCOPE_AGENT);
            }

            // ---- dout (off the publication path) ----
            dout[((size_t)gb * S + s) * (2 * H) + dir * H + j0 + gj] = h2;
            if (t == S - 1) {
                size_t base = (size_t)B * S * 2 * H;
                dout[base + dir * 2 * B * H + gb * H + j0 + gj] = h2;
                dout[base + dir * 2 * B * H + B * H + gb * H + j0 + gj] = c2;
            }
        }
    } else {
        // ---- W waves: free-running xz producer, fs = wave-4, +4 ----
        const f32x4 zero4 = {0.f, 0.f, 0.f, 0.f};
        for (int fs = wave - 4; fs < S; fs += 4) {
            if (fs >= 8) {   // wait until gate passed step fs-8 (slot free)
                const unsigned need = 4u * (unsigned)(fs - 7);
                while (*(volatile unsigned*)&gcnt < need)
                    __builtin_amdgcn_s_sleep(1);
                asm volatile("" ::: "memory");
            }
            const int s2 = dir ? (S - 1 - fs) : fs;
            f32x4 a00 = zero4, a01 = zero4, a10 = zero4, a11 = zero4;
            for (int sl = 0; sl < 4; ++sl) {
                const unsigned short* wbase =
                    wbufW + (((size_t)blk * 4 + sl) * 16) * 512 + lane * 8;
                bf16x8 wf[16];
#pragma unroll
                for (int f = 0; f < 16; ++f) wf[f] = *(const bf16x8*)(wbase + f * 512);
                const unsigned short* A0 =
                    xbf + ((size_t)arow * S + s2) * H + sl * 256 + akoff;
#pragma unroll
                for (int ks = 0; ks < 8; ++ks) {
                    bf16x8 x0 = *(const bf16x8*)(A0 + ks * 32);
                    bf16x8 x1 = *(const bf16x8*)(A0 + (size_t)16 * S * H + ks * 32);
                    a00 = MFMA(x0, wf[ks*2+0], a00); a01 = MFMA(x0, wf[ks*2+1], a01);
                    a10 = MFMA(x1, wf[ks*2+0], a10); a11 = MFMA(x1, wf[ks*2+1], a11);
                }
            }
            const int slot = fs & 7;
#pragma unroll
            for (int r = 0; r < 4; ++r) {
                ring[slot][drow + r][dcol]           = f2bf(a00[r] + wb0);
                ring[slot][drow + r][16 + dcol]      = f2bf(a01[r] + wb1);
                ring[slot][16 + drow + r][dcol]      = f2bf(a10[r] + wb0);
                ring[slot][16 + drow + r][16 + dcol] = f2bf(a11[r] + wb1);
            }
            asm volatile("s_waitcnt lgkmcnt(0)" ::: "memory");
            if (lane == 0) *(volatile int*)&ring_ready[slot] = fs + 1;
        }
    }
}

// =====================================================================
// Host side
// =====================================================================
extern "C" void kernel_launch(void* const* d_in, const int* in_sizes, int n_in,
                              void* d_out, int out_size, void* d_ws, size_t ws_size,
                              hipStream_t stream)
{
    const float* x   = (const float*)d_in[0];
    const float* pad = (const float*)d_in[1];
    const float* Wfw = (const float*)d_in[2];
    const float* Ufw = (const float*)d_in[3];
    const float* bfw = (const float*)d_in[4];
    const float* Wbw = (const float*)d_in[5];
    const float* Ubw = (const float*)d_in[6];
    const float* bbw = (const float*)d_in[7];
    float* out = (float*)d_out;

    char* w = (char*)d_ws;
    unsigned short* wbufW = (unsigned short*)w;                     // 16.8 MB
    unsigned short* wbufU = wbufW + (size_t)1048576 * 8;            // 16.8 MB
    unsigned short* xbf   = wbufU + (size_t)1048576 * 8;            // 33.6 MB
    unsigned short* hhist = xbf + (size_t)B * S * H;                // 513 x 128 KB
    unsigned int*   gen   = (unsigned int*)(hhist + (size_t)(S + 1) * HSLOT); // 64 uints

    // zero h slot 0 and gen counters (deterministic per call)
    hipMemsetAsync(hhist, 0, (size_t)HSLOT * sizeof(unsigned short), stream);
    hipMemsetAsync(gen, 0, 64 * sizeof(unsigned int), stream);

    prep_x<<<8192, 256, 0, stream>>>(x, xbf);
    prep_weights<<<4096, 256, 0, stream>>>(Wfw, Wbw, wbufW);
    prep_weights<<<4096, 256, 0, stream>>>(Ufw, Ubw, wbufU);

    void* args[] = { (void*)&wbufU, (void*)&wbufW, (void*)&xbf, (void*)&hhist,
                     (void*)&gen, (void*)&pad,
                     (void*)&bfw, (void*)&bbw, (void*)&out };
    hipLaunchCooperativeKernel((void*)lstm_persist, dim3(NBLK), dim3(512),
                               args, 0, stream);
}

// Round 9
// 7352.288 us; speedup vs baseline: 1.0398x; 1.0022x over previous
//
#include <hip/hip_runtime.h>
#include <hip/hip_bf16.h>

#define B 32
#define S 512
#define H 1024
#define G 4096          // 4*H
#define NBLK 256
#define HSLOT 65536     // shorts per h slot (2 dirs x B x H)

typedef __attribute__((ext_vector_type(8))) short bf16x8;
typedef __attribute__((ext_vector_type(8))) unsigned short u16x8;
typedef __attribute__((ext_vector_type(4))) float f32x4;

__device__ __forceinline__ unsigned short f2bf(float v) {
    __hip_bfloat16 b = __float2bfloat16(v);
    return *reinterpret_cast<unsigned short*>(&b);
}
__device__ __forceinline__ float bf2f(unsigned short u) {
    union { float f; unsigned int i; } v; v.i = ((unsigned int)u) << 16; return v.f;
}
#define MFMA(a, b, c) __builtin_amdgcn_mfma_f32_16x16x32_bf16(a, b, c, 0, 0, 0)

// =====================================================================
// prep_weights: fragment-ordered bf16 weights for one matrix pair (fw,bw).
// chunk idx = ((blk*4 + w)*16 + f)*64 + lane, 8 bf16/chunk; 1,048,576 chunks.
// =====================================================================
__global__ __launch_bounds__(256)
void prep_weights(const float* __restrict__ fw, const float* __restrict__ bw,
                  unsigned short* __restrict__ dst)
{
    size_t idx = (size_t)blockIdx.x * 256 + threadIdx.x;
    int lane = idx & 63;
    int f    = (idx >> 6) & 15;
    int w    = (idx >> 10) & 3;
    int blk  = (int)(idx >> 12);
    int dir  = blk >> 7, jg = blk & 127;
    int ks = f >> 1, ct = f & 1;

    int c  = ct * 16 + (lane & 15);
    int g  = (c >> 3) * H + jg * 8 + (c & 7);
    int kk = w * 256 + ks * 32 + ((lane >> 4) * 8);

    const float* src = dir ? bw : fw;
    u16x8 o;
#pragma unroll
    for (int i = 0; i < 8; ++i)
        o[i] = f2bf(src[(size_t)(kk + i) * G + g]);
    *(u16x8*)&dst[idx * 8] = o;
}

__global__ __launch_bounds__(256)
void prep_x(const float* __restrict__ x, unsigned short* __restrict__ xbf)
{
    size_t i8 = ((size_t)blockIdx.x * 256 + threadIdx.x) * 8;
    float4 v0 = *(const float4*)&x[i8];
    float4 v1 = *(const float4*)&x[i8 + 4];
    u16x8 o;
    o[0] = f2bf(v0.x); o[1] = f2bf(v0.y); o[2] = f2bf(v0.z); o[3] = f2bf(v0.w);
    o[4] = f2bf(v1.x); o[5] = f2bf(v1.y); o[6] = f2bf(v1.z); o[7] = f2bf(v1.w);
    *(u16x8*)&xbf[i8] = o;
}

// =====================================================================
// lstm_persist: one cooperative kernel, all 512 steps, no __syncthreads
// in the loop.
// 256 blocks x 512 threads. Block (dir,jg) owns 32 gate-cols.
// Waves 0-3 (U+gate): per step t:
//   wave0 polls gen[dir] >= 128*t (single LLC line) -> LDS token;
//   h(t-1) @ U (regular pipelined loads from hhist[t], U frags in LDS);
//   LDS counter barrier among the 4 waves; gate: ring + partials -> h,c;
//   h -> hhist[t+1] via 8B agent stores; vmcnt(0); gcnt++; 4th wave
//   fetch_adds gen[dir]; dout stores issued after publication.
// Waves 4-7 (W): free-running fs-loop (fs = wave-4, +4 each iter): full-K
//   x@W+b -> ring[fs&7] (LDS), paced by gcnt (slot freed when gate passed
//   fs-8), published via ring_ready generation flags. Never on the
//   critical path (>=4-step slack).
// =====================================================================
__global__ __launch_bounds__(512, 1)
void lstm_persist(const unsigned short* __restrict__ wbufU,
                  const unsigned short* __restrict__ wbufW,
                  const unsigned short* __restrict__ xbf,
                  unsigned short* __restrict__ hhist,  // 513 slots x HSLOT
                  unsigned int* __restrict__ gen,      // [dir*32]
                  const float* __restrict__ pad,
                  const float* __restrict__ bfw, const float* __restrict__ bbw,
                  float* __restrict__ dout)
{
    const int blk = blockIdx.x;
    const int dir = blk >> 7;
    const int jg  = blk & 127;
    const int j0  = jg * 8;
    const int tid = threadIdx.x;
    const int wave = tid >> 6;
    const int lane = tid & 63;

    __shared__ short Uw[32768];                  // 64 KB U frags (wave-local regions)
    __shared__ float red[4][2][16][33];          // U partials
    __shared__ unsigned short ring[8][32][36];   // xz lookahead (bf16, bias folded)
    __shared__ unsigned rcnt;                    // red arrivals (monotone, 4/step)
    __shared__ unsigned gcnt;                    // gate-wave publishes (monotone, 4/step)
    __shared__ unsigned tok;                     // gen-poll relay
    __shared__ int ring_ready[8];                // slot generation = fs+1

    if (tid == 0) { rcnt = 0; gcnt = 0; tok = 0; }
    if (tid < 8) ring_ready[tid] = 0;
    __syncthreads();   // the only block-wide barrier (init)

    const int arow  = lane & 15;
    const int akoff = (lane >> 4) * 8;
    const int drow  = (lane >> 4) * 4;
    const int dcol  = lane & 15;
    const float* bsrc = dir ? bbw : bfw;
    const float wb0 = bsrc[(dcol >> 3) * H + j0 + (dcol & 7)];
    const float wb1 = bsrc[(((16 + dcol) >> 3)) * H + j0 + ((16 + dcol) & 7)];

    if (wave < 4) {
        // ---- load this wave's U region into LDS (16 KB, wave-local) ----
        {
            const unsigned short* src = wbufU + (((size_t)blk * 4 + wave) * 16) * 512 + lane * 8;
#pragma unroll
            for (int f = 0; f < 16; ++f)
                *(u16x8*)&Uw[((wave * 16 + f) * 64 + lane) * 8] = *(const u16x8*)(src + f * 512);
        }

        float hst = 0.f, cst = 0.f;
        const int gb  = (tid >> 3) & 31;
        const int gj  = tid & 7;
        const int gbt = gb >> 4, grow = gb & 15;
        const f32x4 zero4 = {0.f, 0.f, 0.f, 0.f};

        for (int t = 0; t < S; ++t) {
            const int s = dir ? (S - 1 - t) : t;
            float pv = pad[gb * S + s];      // early issue, hidden under poll/MFMA

            // ---- wait for step t-1 publications of this direction ----
            if (t) {
                if (wave == 0) {
                    const unsigned tgt = (unsigned)(128 * t);
                    while (__hip_atomic_load(&gen[dir * 32], __ATOMIC_RELAXED,
                                             __HIP_MEMORY_SCOPE_AGENT) < tgt)
                        __builtin_amdgcn_s_sleep(1);
                    asm volatile("" ::: "memory");
                    if (lane == 0) *(volatile unsigned*)&tok = (unsigned)t;
                } else {
                    while (*(volatile unsigned*)&tok < (unsigned)t) {}
                }
                asm volatile("" ::: "memory");
            }

            // ---- U phase: h(t-1) @ U, K-slice wave*256, regular loads ----
            f32x4 u00 = zero4, u01 = zero4, u10 = zero4, u11 = zero4;
            const unsigned short* hb = hhist + (size_t)t * HSLOT
                                     + ((size_t)(dir * B) + arow) * H + wave * 256 + akoff;
#pragma unroll
            for (int ks = 0; ks < 8; ++ks) {
                bf16x8 a0 = *(const bf16x8*)(hb + ks * 32);
                bf16x8 a1 = *(const bf16x8*)(hb + 16 * H + ks * 32);
                bf16x8 b0 = *(const bf16x8*)&Uw[((wave * 16 + ks * 2 + 0) * 64 + lane) * 8];
                bf16x8 b1 = *(const bf16x8*)&Uw[((wave * 16 + ks * 2 + 1) * 64 + lane) * 8];
                u00 = MFMA(a0, b0, u00); u01 = MFMA(a0, b1, u01);
                u10 = MFMA(a1, b0, u10); u11 = MFMA(a1, b1, u11);
            }
#pragma unroll
            for (int r = 0; r < 4; ++r) {
                red[wave][0][drow + r][dcol]      = u00[r];
                red[wave][0][drow + r][16 + dcol] = u01[r];
                red[wave][1][drow + r][dcol]      = u10[r];
                red[wave][1][drow + r][16 + dcol] = u11[r];
            }
            asm volatile("s_waitcnt lgkmcnt(0)" ::: "memory");
            if (lane == 0) atomicAdd(&rcnt, 1u);
            {
                const unsigned need = 4u * (unsigned)(t + 1);
                while (*(volatile unsigned*)&rcnt < need) {}
                asm volatile("" ::: "memory");
            }

            // ---- wait for ring slot t (normally ready long ago) ----
            while (*(volatile int*)&ring_ready[t & 7] < t + 1) {}
            asm volatile("" ::: "memory");

            // ---- gate ----
            float z[4];
#pragma unroll
            for (int q = 0; q < 4; ++q) {
                const int c = q * 8 + gj;
                float zz = bf2f(ring[t & 7][gb][c]);
#pragma unroll
                for (int w = 0; w < 4; ++w) zz += red[w][gbt][grow][c];
                z[q] = zz;
            }
            float ig = 1.f / (1.f + expf(-z[0]));
            float fg = 1.f / (1.f + expf(-z[1]));
            float gg = tanhf(z[2]);
            float og = 1.f / (1.f + expf(-z[3]));

            float m  = 1.f - pv;
            float cn = fg * cst + ig * gg;
            float hn = og * tanhf(cn);
            float h2 = fmaf(m, hn - hst, hst);
            float c2 = fmaf(m, cn - cst, cst);
            hst = h2; cst = c2;

            // ---- publish h(t) -> hhist[t+1] (8B packed agent stores) ----
            unsigned u = (unsigned)f2bf(h2);
            const int gl = lane & ~3;
            unsigned v0 = (unsigned)__shfl((int)u, gl + 0);
            unsigned v1 = (unsigned)__shfl((int)u, gl + 1);
            unsigned v2 = (unsigned)__shfl((int)u, gl + 2);
            unsigned v3 = (unsigned)__shfl((int)u, gl + 3);
            if ((lane & 3) == 0) {
                unsigned long long pk = (unsigned long long)(v0 & 0xffffu)
                                      | ((unsigned long long)(v1 & 0xffffu) << 16)
                                      | ((unsigned long long)(v2 & 0xffffu) << 32)
                                      | ((unsigned long long)(v3 & 0xffffu) << 48);
                unsigned long long* hp = (unsigned long long*)
                    (hhist + (size_t)(t + 1) * HSLOT
                           + ((size_t)(dir * B) + gb) * H + j0 + gj);
                __hip_atomic_store(hp, pk, __ATOMIC_RELAXED, __HIP_MEMORY_SCOPE_AGENT);
            }
            asm volatile("s_waitcnt vmcnt(0)" ::: "memory");
            if (lane == 0) {
                unsigned old = atomicAdd(&gcnt, 1u);
                if (old == 4u * (unsigned)t + 3u)
                    __hip_atomic_fetch_add(&gen[dir * 32], 1u,
                                           __ATOMIC_RELAXED, __HIP_MEMORY_SCOPE_AGENT);
            }

            // ---- dout (off the publication path) ----
            dout[((size_t)gb * S + s) * (2 * H) + dir * H + j0 + gj] = h2;
            if (t == S - 1) {
                size_t base = (size_t)B * S * 2 * H;
                dout[base + dir * 2 * B * H + gb * H + j0 + gj] = h2;
                dout[base + dir * 2 * B * H + B * H + gb * H + j0 + gj] = c2;
            }
        }
    } else {
        // ---- W waves: free-running xz producer, fs = wave-4, +4 ----
        const f32x4 zero4 = {0.f, 0.f, 0.f, 0.f};
        for (int fs = wave - 4; fs < S; fs += 4) {
            if (fs >= 8) {   // wait until gate passed step fs-8 (slot free)
                const unsigned need = 4u * (unsigned)(fs - 7);
                while (*(volatile unsigned*)&gcnt < need)
                    __builtin_amdgcn_s_sleep(1);
                asm volatile("" ::: "memory");
            }
            const int s2 = dir ? (S - 1 - fs) : fs;
            f32x4 a00 = zero4, a01 = zero4, a10 = zero4, a11 = zero4;
            for (int sl = 0; sl < 4; ++sl) {
                const unsigned short* wbase =
                    wbufW + (((size_t)blk * 4 + sl) * 16) * 512 + lane * 8;
                bf16x8 wf[16];
#pragma unroll
                for (int f = 0; f < 16; ++f) wf[f] = *(const bf16x8*)(wbase + f * 512);
                const unsigned short* A0 =
                    xbf + ((size_t)arow * S + s2) * H + sl * 256 + akoff;
#pragma unroll
                for (int ks = 0; ks < 8; ++ks) {
                    bf16x8 x0 = *(const bf16x8*)(A0 + ks * 32);
                    bf16x8 x1 = *(const bf16x8*)(A0 + (size_t)16 * S * H + ks * 32);
                    a00 = MFMA(x0, wf[ks*2+0], a00); a01 = MFMA(x0, wf[ks*2+1], a01);
                    a10 = MFMA(x1, wf[ks*2+0], a10); a11 = MFMA(x1, wf[ks*2+1], a11);
                }
            }
            const int slot = fs & 7;
#pragma unroll
            for (int r = 0; r < 4; ++r) {
                ring[slot][drow + r][dcol]           = f2bf(a00[r] + wb0);
                ring[slot][drow + r][16 + dcol]      = f2bf(a01[r] + wb1);
                ring[slot][16 + drow + r][dcol]      = f2bf(a10[r] + wb0);
                ring[slot][16 + drow + r][16 + dcol] = f2bf(a11[r] + wb1);
            }
            asm volatile("s_waitcnt lgkmcnt(0)" ::: "memory");
            if (lane == 0) *(volatile int*)&ring_ready[slot] = fs + 1;
        }
    }
}

// =====================================================================
// Host side
// =====================================================================
extern "C" void kernel_launch(void* const* d_in, const int* in_sizes, int n_in,
                              void* d_out, int out_size, void* d_ws, size_t ws_size,
                              hipStream_t stream)
{
    const float* x   = (const float*)d_in[0];
    const float* pad = (const float*)d_in[1];
    const float* Wfw = (const float*)d_in[2];
    const float* Ufw = (const float*)d_in[3];
    const float* bfw = (const float*)d_in[4];
    const float* Wbw = (const float*)d_in[5];
    const float* Ubw = (const float*)d_in[6];
    const float* bbw = (const float*)d_in[7];
    float* out = (float*)d_out;

    char* w = (char*)d_ws;
    unsigned short* wbufW = (unsigned short*)w;                     // 16.8 MB
    unsigned short* wbufU = wbufW + (size_t)1048576 * 8;            // 16.8 MB
    unsigned short* xbf   = wbufU + (size_t)1048576 * 8;            // 33.6 MB
    unsigned short* hhist = xbf + (size_t)B * S * H;                // 513 x 128 KB
    unsigned int*   gen   = (unsigned int*)(hhist + (size_t)(S + 1) * HSLOT); // 64 uints

    // zero h slot 0 and gen counters (deterministic per call)
    hipMemsetAsync(hhist, 0, (size_t)HSLOT * sizeof(unsigned short), stream);
    hipMemsetAsync(gen, 0, 64 * sizeof(unsigned int), stream);

    prep_x<<<8192, 256, 0, stream>>>(x, xbf);
    prep_weights<<<4096, 256, 0, stream>>>(Wfw, Wbw, wbufW);
    prep_weights<<<4096, 256, 0, stream>>>(Ufw, Ubw, wbufU);

    void* args[] = { (void*)&wbufU, (void*)&wbufW, (void*)&xbf, (void*)&hhist,
                     (void*)&gen, (void*)&pad,
                     (void*)&bfw, (void*)&bbw, (void*)&out };
    hipLaunchCooperativeKernel((void*)lstm_persist, dim3(NBLK), dim3(512),
                               args, 0, stream);
}

// Round 10
// 3358.113 us; speedup vs baseline: 2.2765x; 2.1894x over previous
//
#include <hip/hip_runtime.h>
#include <hip/hip_bf16.h>

#define B 32
#define S 512
#define H 1024
#define G 4096          // 4*H
#define NBLK 256
#define HSLOT 65536     // shorts per h slot (2 dirs x B x H)

typedef __attribute__((ext_vector_type(8))) short bf16x8;
typedef __attribute__((ext_vector_type(8))) unsigned short u16x8;
typedef __attribute__((ext_vector_type(4))) float f32x4;

__device__ __forceinline__ unsigned short f2bf(float v) {
    __hip_bfloat16 b = __float2bfloat16(v);
    return *reinterpret_cast<unsigned short*>(&b);
}
__device__ __forceinline__ float bf2f(unsigned short u) {
    union { float f; unsigned int i; } v; v.i = ((unsigned int)u) << 16; return v.f;
}
#define MFMA(a, b, c) __builtin_amdgcn_mfma_f32_16x16x32_bf16(a, b, c, 0, 0, 0)
#define ALOAD(p)    __hip_atomic_load((p),  __ATOMIC_RELAXED, __HIP_MEMORY_SCOPE_AGENT)
#define ASTORE(p,v) __hip_atomic_store((p), (v), __ATOMIC_RELAXED, __HIP_MEMORY_SCOPE_AGENT)

// =====================================================================
// prep_weights: fragment-ordered bf16 weights for one matrix pair (fw,bw).
// chunk idx = ((blk*4 + w)*16 + f)*64 + lane, 8 bf16/chunk; 1,048,576 chunks.
// =====================================================================
__global__ __launch_bounds__(256)
void prep_weights(const float* __restrict__ fw, const float* __restrict__ bw,
                  unsigned short* __restrict__ dst)
{
    size_t idx = (size_t)blockIdx.x * 256 + threadIdx.x;
    int lane = idx & 63;
    int f    = (idx >> 6) & 15;
    int w    = (idx >> 10) & 3;
    int blk  = (int)(idx >> 12);
    int dir  = blk >> 7, jg = blk & 127;
    int ks = f >> 1, ct = f & 1;

    int c  = ct * 16 + (lane & 15);
    int g  = (c >> 3) * H + jg * 8 + (c & 7);
    int kk = w * 256 + ks * 32 + ((lane >> 4) * 8);

    const float* src = dir ? bw : fw;
    u16x8 o;
#pragma unroll
    for (int i = 0; i < 8; ++i)
        o[i] = f2bf(src[(size_t)(kk + i) * G + g]);
    *(u16x8*)&dst[idx * 8] = o;
}

__global__ __launch_bounds__(256)
void prep_x(const float* __restrict__ x, unsigned short* __restrict__ xbf)
{
    size_t i8 = ((size_t)blockIdx.x * 256 + threadIdx.x) * 8;
    float4 v0 = *(const float4*)&x[i8];
    float4 v1 = *(const float4*)&x[i8 + 4];
    u16x8 o;
    o[0] = f2bf(v0.x); o[1] = f2bf(v0.y); o[2] = f2bf(v0.z); o[3] = f2bf(v0.w);
    o[4] = f2bf(v1.x); o[5] = f2bf(v1.y); o[6] = f2bf(v1.z); o[7] = f2bf(v1.w);
    *(u16x8*)&xbf[i8] = o;
}

// =====================================================================
// lstm_persist: one cooperative kernel, all 512 steps.
// 256 blocks x 512 threads. Block (dir,jg) owns 32 gate-cols.
// Barrier topology (R5-proven): per-block padded flag (plain store, after
// vmcnt(0) of h stores) -> per-dir master (blk 0 / blk 128, wave0) scans
// 128 flags -> plain-stores gen[dir] -> all other blocks' wave0 poll the
// single-writer gen line -> LDS token relay to waves 1-3.
// Datapath (R9-proven): h history buffer (fresh 128 KB slot per step,
// regular pipelined bf16x8 loads); U frags in LDS; W-waves free-run the
// x@W lookahead into an 8-slot LDS ring paced by gcnt (4+ steps slack).
// =====================================================================
__global__ __launch_bounds__(512, 1)
void lstm_persist(const unsigned short* __restrict__ wbufU,
                  const unsigned short* __restrict__ wbufW,
                  const unsigned short* __restrict__ xbf,
                  unsigned short* __restrict__ hhist,  // 513 slots x HSLOT
                  unsigned int* __restrict__ flags,    // 256 x 16 (64B stride)
                  unsigned int* __restrict__ gen,      // [dir*32]
                  const float* __restrict__ pad,
                  const float* __restrict__ bfw, const float* __restrict__ bbw,
                  float* __restrict__ dout)
{
    const int blk = blockIdx.x;
    const int dir = blk >> 7;
    const int jg  = blk & 127;
    const int j0  = jg * 8;
    const int tid = threadIdx.x;
    const int wave = tid >> 6;
    const int lane = tid & 63;
    const bool is_master = (jg == 0);   // blk 0 (dir0) and blk 128 (dir1)

    __shared__ short Uw[32768];                  // 64 KB U frags (wave-local regions)
    __shared__ float red[4][2][16][33];          // U partials
    __shared__ unsigned short ring[8][32][36];   // xz lookahead (bf16, bias folded)
    __shared__ unsigned rcnt;                    // red arrivals (monotone, 4/step)
    __shared__ unsigned gcnt;                    // gate publishes (monotone, 4/step)
    __shared__ unsigned tok;                     // gen-poll relay
    __shared__ int ring_ready[8];                // slot generation = fs+1

    if (tid == 0) { rcnt = 0; gcnt = 0; tok = 0; }
    if (tid < 8) ring_ready[tid] = 0;
    __syncthreads();   // the only block-wide barrier (init)

    const int arow  = lane & 15;
    const int akoff = (lane >> 4) * 8;
    const int drow  = (lane >> 4) * 4;
    const int dcol  = lane & 15;
    const float* bsrc = dir ? bbw : bfw;
    const float wb0 = bsrc[(dcol >> 3) * H + j0 + (dcol & 7)];
    const float wb1 = bsrc[(((16 + dcol) >> 3)) * H + j0 + ((16 + dcol) & 7)];

    if (wave < 4) {
        // ---- load this wave's U region into LDS (16 KB, wave-local) ----
        {
            const unsigned short* src = wbufU + (((size_t)blk * 4 + wave) * 16) * 512 + lane * 8;
#pragma unroll
            for (int f = 0; f < 16; ++f)
                *(u16x8*)&Uw[((wave * 16 + f) * 64 + lane) * 8] = *(const u16x8*)(src + f * 512);
        }

        float hst = 0.f, cst = 0.f;
        const int gb  = (tid >> 3) & 31;
        const int gj  = tid & 7;
        const int gbt = gb >> 4, grow = gb & 15;
        const f32x4 zero4 = {0.f, 0.f, 0.f, 0.f};

        for (int t = 0; t < S; ++t) {
            const int s = dir ? (S - 1 - t) : t;
            float pv = pad[gb * S + s];      // early issue, hidden under poll

            // ---- wait for step t-1 publications of this direction ----
            if (t) {
                if (wave == 0) {
                    if (is_master) {
                        // scan this dir's 128 flags (64 lanes x 2, 64B stride)
                        const unsigned* fb = flags + (size_t)dir * 128 * 16;
                        bool allok;
                        do {
                            unsigned v0 = ALOAD(&fb[(lane * 2 + 0) * 16]);
                            unsigned v1 = ALOAD(&fb[(lane * 2 + 1) * 16]);
                            allok = __all(v0 >= (unsigned)t && v1 >= (unsigned)t);
                            if (!allok) __builtin_amdgcn_s_sleep(1);
                        } while (!allok);
                        if (lane == 0) ASTORE(&gen[dir * 32], (unsigned)t);
                    } else {
                        // poll single-writer broadcast line
                        while (ALOAD(&gen[dir * 32]) < (unsigned)t)
                            __builtin_amdgcn_s_sleep(1);
                    }
                    asm volatile("" ::: "memory");
                    if (lane == 0) *(volatile unsigned*)&tok = (unsigned)t;
                } else {
                    while (*(volatile unsigned*)&tok < (unsigned)t) {}
                }
                asm volatile("" ::: "memory");
            }

            // ---- U phase: h(t-1) @ U, K-slice wave*256, pipelined loads ----
            f32x4 u00 = zero4, u01 = zero4, u10 = zero4, u11 = zero4;
            const unsigned short* hb = hhist + (size_t)t * HSLOT
                                     + ((size_t)(dir * B) + arow) * H + wave * 256 + akoff;
#pragma unroll
            for (int ks = 0; ks < 8; ++ks) {
                bf16x8 a0 = *(const bf16x8*)(hb + ks * 32);
                bf16x8 a1 = *(const bf16x8*)(hb + 16 * H + ks * 32);
                bf16x8 b0 = *(const bf16x8*)&Uw[((wave * 16 + ks * 2 + 0) * 64 + lane) * 8];
                bf16x8 b1 = *(const bf16x8*)&Uw[((wave * 16 + ks * 2 + 1) * 64 + lane) * 8];
                u00 = MFMA(a0, b0, u00); u01 = MFMA(a0, b1, u01);
                u10 = MFMA(a1, b0, u10); u11 = MFMA(a1, b1, u11);
            }
#pragma unroll
            for (int r = 0; r < 4; ++r) {
                red[wave][0][drow + r][dcol]      = u00[r];
                red[wave][0][drow + r][16 + dcol] = u01[r];
                red[wave][1][drow + r][dcol]      = u10[r];
                red[wave][1][drow + r][16 + dcol] = u11[r];
            }
            asm volatile("s_waitcnt lgkmcnt(0)" ::: "memory");
            if (lane == 0) atomicAdd(&rcnt, 1u);
            {
                const unsigned need = 4u * (unsigned)(t + 1);
                while (*(volatile unsigned*)&rcnt < need) {}
                asm volatile("" ::: "memory");
            }

            // ---- ring slot t (normally ready 4+ steps ago) ----
            while (*(volatile int*)&ring_ready[t & 7] < t + 1) {}
            asm volatile("" ::: "memory");

            // ---- gate ----
            float z[4];
#pragma unroll
            for (int q = 0; q < 4; ++q) {
                const int c = q * 8 + gj;
                float zz = bf2f(ring[t & 7][gb][c]);
#pragma unroll
                for (int w = 0; w < 4; ++w) zz += red[w][gbt][grow][c];
                z[q] = zz;
            }
            float ig = 1.f / (1.f + expf(-z[0]));
            float fg = 1.f / (1.f + expf(-z[1]));
            float gg = tanhf(z[2]);
            float og = 1.f / (1.f + expf(-z[3]));

            float m  = 1.f - pv;
            float cn = fg * cst + ig * gg;
            float hn = og * tanhf(cn);
            float h2 = fmaf(m, hn - hst, hst);
            float c2 = fmaf(m, cn - cst, cst);
            hst = h2; cst = c2;

            // ---- publish h(t) -> hhist[t+1] (8B packed agent stores) ----
            unsigned u = (unsigned)f2bf(h2);
            const int gl = lane & ~3;
            unsigned v0 = (unsigned)__shfl((int)u, gl + 0);
            unsigned v1 = (unsigned)__shfl((int)u, gl + 1);
            unsigned v2 = (unsigned)__shfl((int)u, gl + 2);
            unsigned v3 = (unsigned)__shfl((int)u, gl + 3);
            if ((lane & 3) == 0) {
                unsigned long long pk = (unsigned long long)(v0 & 0xffffu)
                                      | ((unsigned long long)(v1 & 0xffffu) << 16)
                                      | ((unsigned long long)(v2 & 0xffffu) << 32)
                                      | ((unsigned long long)(v3 & 0xffffu) << 48);
                unsigned long long* hp = (unsigned long long*)
                    (hhist + (size_t)(t + 1) * HSLOT
                           + ((size_t)(dir * B) + gb) * H + j0 + gj);
                ASTORE(hp, pk);
            }
            asm volatile("s_waitcnt vmcnt(0)" ::: "memory");
            if (lane == 0) {
                unsigned old = atomicAdd(&gcnt, 1u);
                if (old == 4u * (unsigned)t + 3u)
                    ASTORE(&flags[(size_t)blk * 16], (unsigned)(t + 1));
            }

            // ---- dout (off the publication path) ----
            dout[((size_t)gb * S + s) * (2 * H) + dir * H + j0 + gj] = h2;
            if (t == S - 1) {
                size_t base = (size_t)B * S * 2 * H;
                dout[base + dir * 2 * B * H + gb * H + j0 + gj] = h2;
                dout[base + dir * 2 * B * H + B * H + gb * H + j0 + gj] = c2;
            }
        }
    } else {
        // ---- W waves: free-running xz producer, fs = wave-4, +4 ----
        const f32x4 zero4 = {0.f, 0.f, 0.f, 0.f};
        for (int fs = wave - 4; fs < S; fs += 4) {
            if (fs >= 8) {   // wait until gate consumed slot (step fs-8 done)
                const unsigned need = 4u * (unsigned)(fs - 7);
                while (*(volatile unsigned*)&gcnt < need)
                    __builtin_amdgcn_s_sleep(2);   // coarse: >=4-step slack
                asm volatile("" ::: "memory");
            }
            const int s2 = dir ? (S - 1 - fs) : fs;
            f32x4 a00 = zero4, a01 = zero4, a10 = zero4, a11 = zero4;
            for (int sl = 0; sl < 4; ++sl) {
                const unsigned short* wbase =
                    wbufW + (((size_t)blk * 4 + sl) * 16) * 512 + lane * 8;
                bf16x8 wf[16];
#pragma unroll
                for (int f = 0; f < 16; ++f) wf[f] = *(const bf16x8*)(wbase + f * 512);
                const unsigned short* A0 =
                    xbf + ((size_t)arow * S + s2) * H + sl * 256 + akoff;
#pragma unroll
                for (int ks = 0; ks < 8; ++ks) {
                    bf16x8 x0 = *(const bf16x8*)(A0 + ks * 32);
                    bf16x8 x1 = *(const bf16x8*)(A0 + (size_t)16 * S * H + ks * 32);
                    a00 = MFMA(x0, wf[ks*2+0], a00); a01 = MFMA(x0, wf[ks*2+1], a01);
                    a10 = MFMA(x1, wf[ks*2+0], a10); a11 = MFMA(x1, wf[ks*2+1], a11);
                }
            }
            const int slot = fs & 7;
#pragma unroll
            for (int r = 0; r < 4; ++r) {
                ring[slot][drow + r][dcol]           = f2bf(a00[r] + wb0);
                ring[slot][drow + r][16 + dcol]      = f2bf(a01[r] + wb1);
                ring[slot][16 + drow + r][dcol]      = f2bf(a10[r] + wb0);
                ring[slot][16 + drow + r][16 + dcol] = f2bf(a11[r] + wb1);
            }
            asm volatile("s_waitcnt lgkmcnt(0)" ::: "memory");
            if (lane == 0) *(volatile int*)&ring_ready[slot] = fs + 1;
        }
    }
}

// =====================================================================
// Host side
// =====================================================================
extern "C" void kernel_launch(void* const* d_in, const int* in_sizes, int n_in,
                              void* d_out, int out_size, void* d_ws, size_t ws_size,
                              hipStream_t stream)
{
    const float* x   = (const float*)d_in[0];
    const float* pad = (const float*)d_in[1];
    const float* Wfw = (const float*)d_in[2];
    const float* Ufw = (const float*)d_in[3];
    const float* bfw = (const float*)d_in[4];
    const float* Wbw = (const float*)d_in[5];
    const float* Ubw = (const float*)d_in[6];
    const float* bbw = (const float*)d_in[7];
    float* out = (float*)d_out;

    char* w = (char*)d_ws;
    unsigned short* wbufW = (unsigned short*)w;                     // 16.8 MB
    unsigned short* wbufU = wbufW + (size_t)1048576 * 8;            // 16.8 MB
    unsigned short* xbf   = wbufU + (size_t)1048576 * 8;            // 33.6 MB
    unsigned short* hhist = xbf + (size_t)B * S * H;                // 513 x 128 KB
    unsigned int*   flags = (unsigned int*)(hhist + (size_t)(S + 1) * HSLOT); // 16 KB
    unsigned int*   gen   = flags + 256 * 16;                       // 64 uints

    // zero h slot 0, flags, gen (deterministic per call)
    hipMemsetAsync(hhist, 0, (size_t)HSLOT * sizeof(unsigned short), stream);
    hipMemsetAsync(flags, 0, (256 * 16 + 64) * sizeof(unsigned int), stream);

    prep_x<<<8192, 256, 0, stream>>>(x, xbf);
    prep_weights<<<4096, 256, 0, stream>>>(Wfw, Wbw, wbufW);
    prep_weights<<<4096, 256, 0, stream>>>(Ufw, Ubw, wbufU);

    void* args[] = { (void*)&wbufU, (void*)&wbufW, (void*)&xbf, (void*)&hhist,
                     (void*)&flags, (void*)&gen, (void*)&pad,
                     (void*)&bfw, (void*)&bbw, (void*)&out };
    hipLaunchCooperativeKernel((void*)lstm_persist, dim3(NBLK), dim3(512),
                               args, 0, stream);
}